// Round 16
// baseline (301.549 us; speedup 1.0000x reference)
//
#include <hip/hip_runtime.h>
#include <math.h>

#define LQ 4096
#define DI 192
#define DS 16
#define NCH 256
#define TCH 16

__device__ __forceinline__ float siluf_(float v) { return v / (1.f + __expf(-v)); }
__device__ __forceinline__ float softplusf_(float v) { return v > 20.f ? v : log1pf(__expf(v)); }

// DPP lane shift within 16-lane rows; bound_ctrl -> 0 at row edges (= image zero-pad).
template <int CTRL>
__device__ __forceinline__ float dpp_shift_(float x) {
    int y = __builtin_amdgcn_update_dpp(0, __float_as_int(x), CTRL, 0xf, 0xf, true);
    return __int_as_float(y);
}
// Async global->LDS. LDS dest = wave-uniform base + lane*size.
__device__ __forceinline__ void async_g2l16_(const float* g, float* l) {
    __builtin_amdgcn_global_load_lds(
        (const __attribute__((address_space(1))) void*)g,
        (__attribute__((address_space(3))) void*)l, 16, 0, 0);
}
__device__ __forceinline__ void async_g2l4_(const float* g, float* l) {
    __builtin_amdgcn_global_load_lds(
        (const __attribute__((address_space(1))) void*)g,
        (__attribute__((address_space(3))) void*)l, 4, 0, 0);
}

// ---------------- K1: in_proj GEMM  xz[b,l,n] = sum_c x[b,c,l] * W[n,c] ----------------
__global__ __launch_bounds__(256) void k1_inproj(const float* __restrict__ x,
    const float* __restrict__ w, float* __restrict__ xi_raw, float* __restrict__ z)
{
    const int l0 = blockIdx.x * 64;
    const int n0 = blockIdx.y * 64;
    const int b  = blockIdx.z;
    __shared__ float xs[96 * 64];    // [c][l]
    __shared__ float wsT[96 * 68];   // [c][n], padded stride 68
    const int tid = threadIdx.x;
    for (int i = tid; i < 96 * 16; i += 256) {
        int c = i >> 4, lq = i & 15;
        *(float4*)&xs[c * 64 + lq * 4] =
            *(const float4*)&x[(b * 96 + c) * LQ + l0 + lq * 4];
    }
    for (int i = tid; i < 64 * 24; i += 256) {
        int n = i / 24, cq = i - n * 24;
        float4 v = *(const float4*)&w[(n0 + n) * 96 + cq * 4];
        wsT[(cq * 4 + 0) * 68 + n] = v.x;
        wsT[(cq * 4 + 1) * 68 + n] = v.y;
        wsT[(cq * 4 + 2) * 68 + n] = v.z;
        wsT[(cq * 4 + 3) * 68 + n] = v.w;
    }
    __syncthreads();
    const int tx = tid & 15;   // n quad
    const int ty = tid >> 4;   // l quad
    float acc[4][4];
#pragma unroll
    for (int i = 0; i < 4; ++i)
#pragma unroll
        for (int j = 0; j < 4; ++j) acc[i][j] = 0.f;
    for (int k = 0; k < 96; ++k) {
        float4 a  = *(const float4*)&xs[k * 64 + ty * 4];
        float4 bb = *(const float4*)&wsT[k * 68 + tx * 4];
        float av[4] = {a.x, a.y, a.z, a.w};
        float bv[4] = {bb.x, bb.y, bb.z, bb.w};
#pragma unroll
        for (int i = 0; i < 4; ++i)
#pragma unroll
            for (int j = 0; j < 4; ++j) acc[i][j] += av[i] * bv[j];
    }
    float* dst = (n0 < DI) ? xi_raw : z;
    const int nn0 = (n0 < DI) ? n0 : (n0 - DI);
#pragma unroll
    for (int i = 0; i < 4; ++i) {
        int l = l0 + ty * 4 + i;
        float4 v = make_float4(acc[i][0], acc[i][1], acc[i][2], acc[i][3]);
        *(float4*)&dst[(b * LQ + l) * DI + nn0 + tx * 4] = v;
    }
}

// ---------------- K2: causal depthwise conv1d + bias + SiLU ----------------
__global__ __launch_bounds__(256) void k2_conv1d(const float* __restrict__ xir,
    const float* __restrict__ cw, const float* __restrict__ cb, float* __restrict__ xi)
{
    int idx = blockIdx.x * 256 + threadIdx.x;       // b*L*DI total
    int d = idx % DI;
    int l = (idx / DI) & (LQ - 1);
    float4 wv = *(const float4*)&cw[d * 4];
    float wk[4] = {wv.x, wv.y, wv.z, wv.w};
    float acc = cb[d];
#pragma unroll
    for (int k = 0; k < 4; ++k) {
        int lp = l - 3 + k;
        if (lp >= 0) acc += wk[k] * xir[idx + (k - 3) * DI];
    }
    xi[idx] = siluf_(acc);
}

// ---------------- K3: x_dbl[b,l,n] = sum_k xi[b,l,k] * xw[n,k], n<38 ----------------
__global__ __launch_bounds__(256) void k3_xdbl(const float* __restrict__ xi,
    const float* __restrict__ xw, float* __restrict__ xdbl)
{
    const int l0 = blockIdx.x * 64;
    const int b  = blockIdx.y;
    __shared__ float sxiT[96 * 68];   // [k(half)][l]
    __shared__ float swx[38 * 196];   // [n][k], padded
    const int tid = threadIdx.x;
    for (int i = tid; i < 38 * 48; i += 256) {
        int n = i / 48, kq = i - n * 48;
        *(float4*)&swx[n * 196 + kq * 4] = *(const float4*)&xw[n * 192 + kq * 4];
    }
    const int lq = tid & 15, ng = tid >> 4;
    float acc[3][4];
#pragma unroll
    for (int p = 0; p < 3; ++p)
#pragma unroll
        for (int i = 0; i < 4; ++i) acc[p][i] = 0.f;
    for (int half = 0; half < 2; ++half) {
        __syncthreads();
        for (int i = tid; i < 64 * 24; i += 256) {
            int l = i / 24, kq = i - l * 24;
            float4 v = *(const float4*)&xi[(b * LQ + l0 + l) * DI + half * 96 + kq * 4];
            sxiT[(kq * 4 + 0) * 68 + l] = v.x;
            sxiT[(kq * 4 + 1) * 68 + l] = v.y;
            sxiT[(kq * 4 + 2) * 68 + l] = v.z;
            sxiT[(kq * 4 + 3) * 68 + l] = v.w;
        }
        __syncthreads();
#pragma unroll
        for (int pass = 0; pass < 3; ++pass) {
            int n = pass * 16 + ng;
            if (n >= 38) continue;
            for (int k = 0; k < 96; ++k) {
                float4 a = *(const float4*)&sxiT[k * 68 + lq * 4];
                float bv = swx[n * 196 + half * 96 + k];
                acc[pass][0] += a.x * bv;
                acc[pass][1] += a.y * bv;
                acc[pass][2] += a.z * bv;
                acc[pass][3] += a.w * bv;
            }
        }
    }
#pragma unroll
    for (int pass = 0; pass < 3; ++pass) {
        int n = pass * 16 + ng;
        if (n >= 38) continue;
#pragma unroll
        for (int i = 0; i < 4; ++i)
            xdbl[(b * LQ + l0 + lq * 4 + i) * 38 + n] = acc[pass][i];
    }
}

// ---------------- K4 v4: scan pass A — thread = d, 16 states, TCH=16 ----------------
__global__ __launch_bounds__(192) void k4_scanA(
    const float* __restrict__ xdbl, const float* __restrict__ xi,
    const float* __restrict__ dtw, const float* __restrict__ dtb,
    const float* __restrict__ alog,
    float* __restrict__ cA, float* __restrict__ cB)
{
    const int ch = blockIdx.x, b = blockIdx.y;
    const int t0 = ch * TCH;
    __shared__ float sxd[TCH * 48];
    const int d = threadIdx.x;
    for (int i = d; i < TCH * 38; i += 192) {
        int t = i / 38, cc = i - t * 38;
        int slot = cc + (cc >= 6 ? 2 : 0);
        sxd[t * 48 + slot] = xdbl[(b * LQ + t0 + t) * 38 + cc];
    }
    float dtw6[6];
#pragma unroll
    for (int r = 0; r < 6; ++r) dtw6[r] = dtw[d * 6 + r];
    const float dtbd = dtb[d];
    float Ads[16];
#pragma unroll
    for (int s = 0; s < 16; ++s) Ads[s] = -__expf(alog[d * 16 + s]);
    float a[16], hb[16];
#pragma unroll
    for (int s = 0; s < 16; ++s) { a[s] = 1.f; hb[s] = 0.f; }
    __syncthreads();
    float xiv_next = xi[(b * LQ + t0) * DI + d];
    for (int t = 0; t < TCH; ++t) {
        float xiv = xiv_next;
        if (t + 1 < TCH) xiv_next = xi[(b * LQ + t0 + t + 1) * DI + d];
        float acc = dtbd;
#pragma unroll
        for (int r = 0; r < 6; ++r) acc = fmaf(sxd[t * 48 + r], dtw6[r], acc);
        float dtv = softplusf_(acc);
        float dtxi = dtv * xiv;
        const float* Bp = &sxd[t * 48 + 8];
        float Bv[16];
#pragma unroll
        for (int q = 0; q < 4; ++q) {
            float4 v = *(const float4*)(Bp + q * 4);
            Bv[q * 4] = v.x; Bv[q * 4 + 1] = v.y; Bv[q * 4 + 2] = v.z; Bv[q * 4 + 3] = v.w;
        }
#pragma unroll
        for (int s = 0; s < 16; ++s) {
            float dA = __expf(dtv * Ads[s]);
            a[s] *= dA;
            hb[s] = fmaf(dA, hb[s], dtxi * Bv[s]);
        }
    }
    int o = ((b * NCH + ch) * DI + d) * 16;
#pragma unroll
    for (int s = 0; s < 16; s += 4) {
        *(float4*)&cA[o + s] = make_float4(a[s], a[s + 1], a[s + 2], a[s + 3]);
        *(float4*)&cB[o + s] = make_float4(hb[s], hb[s + 1], hb[s + 2], hb[s + 3]);
    }
}

// ---------------- K5: sequential combine over chunks -> h_init per chunk ----------------
__global__ __launch_bounds__(256) void k5_combine(const float* cA,
    const float* __restrict__ cB, float* hinit)
{
    int gid = blockIdx.x * 256 + threadIdx.x;   // 4*192*16 = 12288
    int b = gid / 3072;
    int rem = gid - b * 3072;
    int base = b * (NCH * 3072) + rem;
    float h = 0.f;
#pragma unroll 8
    for (int c = 0; c < NCH; ++c) {
        int o = base + c * 3072;
        float av = cA[o];
        float bv = cB[o];
        hinit[o] = h;
        h = fmaf(av, h, bv);
    }
}

// ---------------- K6 v4: scan pass C — thread = d, h[16], TCH=16 ----------------
__global__ __launch_bounds__(192) void k6_scanC(
    const float* __restrict__ xdbl, const float* __restrict__ xi,
    const float* __restrict__ z, const float* __restrict__ dtw,
    const float* __restrict__ dtb, const float* __restrict__ alog,
    const float* __restrict__ Dp, const float* __restrict__ hinit,
    float* __restrict__ yg)
{
    const int ch = blockIdx.x, b = blockIdx.y;
    const int t0 = ch * TCH;
    __shared__ float sxd[TCH * 48];
    const int d = threadIdx.x;
    for (int i = d; i < TCH * 38; i += 192) {
        int t = i / 38, cc = i - t * 38;
        int slot = cc + (cc >= 6 ? 2 : 0);
        sxd[t * 48 + slot] = xdbl[(b * LQ + t0 + t) * 38 + cc];
    }
    float dtw6[6];
#pragma unroll
    for (int r = 0; r < 6; ++r) dtw6[r] = dtw[d * 6 + r];
    const float dtbd = dtb[d];
    const float Dd = Dp[d];
    float Ads[16];
#pragma unroll
    for (int s = 0; s < 16; ++s) Ads[s] = -__expf(alog[d * 16 + s]);
    float h[16];
    const int o = ((b * NCH + ch) * DI + d) * 16;
#pragma unroll
    for (int s = 0; s < 16; s += 4) {
        float4 v = *(const float4*)&hinit[o + s];
        h[s] = v.x; h[s + 1] = v.y; h[s + 2] = v.z; h[s + 3] = v.w;
    }
    __syncthreads();
    float xiv_next = xi[(b * LQ + t0) * DI + d];
    float zv_next  = z[(b * LQ + t0) * DI + d];
    for (int t = 0; t < TCH; ++t) {
        float xiv = xiv_next, zv = zv_next;
        if (t + 1 < TCH) {
            xiv_next = xi[(b * LQ + t0 + t + 1) * DI + d];
            zv_next  = z[(b * LQ + t0 + t + 1) * DI + d];
        }
        float acc = dtbd;
#pragma unroll
        for (int r = 0; r < 6; ++r) acc = fmaf(sxd[t * 48 + r], dtw6[r], acc);
        float dtv = softplusf_(acc);
        float dtxi = dtv * xiv;
        const float* Bp = &sxd[t * 48 + 8];
        const float* Cp = &sxd[t * 48 + 24];
        float Bv[16], Cv[16];
#pragma unroll
        for (int q = 0; q < 4; ++q) {
            float4 vb = *(const float4*)(Bp + q * 4);
            float4 vc = *(const float4*)(Cp + q * 4);
            Bv[q * 4] = vb.x; Bv[q * 4 + 1] = vb.y; Bv[q * 4 + 2] = vb.z; Bv[q * 4 + 3] = vb.w;
            Cv[q * 4] = vc.x; Cv[q * 4 + 1] = vc.y; Cv[q * 4 + 2] = vc.z; Cv[q * 4 + 3] = vc.w;
        }
        float y0 = 0.f, y1 = 0.f, y2 = 0.f, y3 = 0.f;
#pragma unroll
        for (int s = 0; s < 16; s += 4) {
            float dA0 = __expf(dtv * Ads[s]);
            float dA1 = __expf(dtv * Ads[s + 1]);
            float dA2 = __expf(dtv * Ads[s + 2]);
            float dA3 = __expf(dtv * Ads[s + 3]);
            h[s]     = fmaf(dA0, h[s],     dtxi * Bv[s]);
            h[s + 1] = fmaf(dA1, h[s + 1], dtxi * Bv[s + 1]);
            h[s + 2] = fmaf(dA2, h[s + 2], dtxi * Bv[s + 2]);
            h[s + 3] = fmaf(dA3, h[s + 3], dtxi * Bv[s + 3]);
            y0 = fmaf(h[s],     Cv[s],     y0);
            y1 = fmaf(h[s + 1], Cv[s + 1], y1);
            y2 = fmaf(h[s + 2], Cv[s + 2], y2);
            y3 = fmaf(h[s + 3], Cv[s + 3], y3);
        }
        float y = (y0 + y1) + (y2 + y3);
        float gate = siluf_(zv);
        yg[(b * LQ + t0 + t) * DI + d] = (y + xiv * Dd) * gate;
    }
}

// ---------------- K7: out_proj GEMM, store transposed to NCHW xm[b,c,l] ----------------
__global__ __launch_bounds__(256) void k7_outproj(const float* __restrict__ yg,
    const float* __restrict__ wo, float* __restrict__ xm)
{
    const int l0 = blockIdx.x * 64;
    const int n0 = blockIdx.y * 32;
    const int b  = blockIdx.z;
    __shared__ float syT[96 * 68];    // [k(half)][l]
    __shared__ float wtT[192 * 36];   // [k][n]
    const int tid = threadIdx.x;
    for (int i = tid; i < 32 * 48; i += 256) {
        int n = i / 48, kq = i - n * 48;
        float4 v = *(const float4*)&wo[(n0 + n) * DI + kq * 4];
        wtT[(kq * 4 + 0) * 36 + n] = v.x;
        wtT[(kq * 4 + 1) * 36 + n] = v.y;
        wtT[(kq * 4 + 2) * 36 + n] = v.z;
        wtT[(kq * 4 + 3) * 36 + n] = v.w;
    }
    const int tx = tid & 15;   // l quad
    const int ty = tid >> 4;   // n pair
    float acc[2][4];
#pragma unroll
    for (int j = 0; j < 2; ++j)
#pragma unroll
        for (int i = 0; i < 4; ++i) acc[j][i] = 0.f;
    for (int half = 0; half < 2; ++half) {
        __syncthreads();
        for (int i = tid; i < 64 * 24; i += 256) {
            int l = i / 24, kq = i - l * 24;
            float4 v = *(const float4*)&yg[(b * LQ + l0 + l) * DI + half * 96 + kq * 4];
            syT[(kq * 4 + 0) * 68 + l] = v.x;
            syT[(kq * 4 + 1) * 68 + l] = v.y;
            syT[(kq * 4 + 2) * 68 + l] = v.z;
            syT[(kq * 4 + 3) * 68 + l] = v.w;
        }
        __syncthreads();
        for (int k = 0; k < 96; ++k) {
            float4 a = *(const float4*)&syT[k * 68 + tx * 4];
            int kk = half * 96 + k;
            float b0 = wtT[kk * 36 + ty * 2 + 0];
            float b1 = wtT[kk * 36 + ty * 2 + 1];
            acc[0][0] += a.x * b0; acc[0][1] += a.y * b0;
            acc[0][2] += a.z * b0; acc[0][3] += a.w * b0;
            acc[1][0] += a.x * b1; acc[1][1] += a.y * b1;
            acc[1][2] += a.z * b1; acc[1][3] += a.w * b1;
        }
    }
#pragma unroll
    for (int j = 0; j < 2; ++j) {
        float4 v = make_float4(acc[j][0], acc[j][1], acc[j][2], acc[j][3]);
        *(float4*)&xm[(b * 96 + n0 + ty * 2 + j) * LQ + l0 + tx * 4] = v;
    }
}

// ---------------- K8 v13: 3x3 conv partials — 8 co/thread, async LDS dbuf ----------------
// Block 256 = 64 spatial (16 col-quads x 4 rows) x 4 wave-groups of 8 co (32 co/block).
// grid (3 co-tiles x 4 ks, 16 y, 4 b) = 768 blocks = 3/CU = 12 waves/CU.
// Per cii per thread: 3 input b128 + 18 weight-broadcast b128 feed 432 FMA — LDS/FMA wave
// ratio ~25% (v12: 67%). acc[8][4]=32 regs; staging stays register-free (async g2l).
#define K8_INQ 384              // staged float4 quads per chunk
#define K8_WNEL 1152            // staged weight floats per chunk (4ci x 9tap x 32co)
__global__ __launch_bounds__(256) void k8_conv3(const float* __restrict__ xm,
    const float* __restrict__ w2, float* __restrict__ pbuf)
{
    const int ks  = blockIdx.x & 3;
    const int co0 = (blockIdx.x >> 2) * 32;
    const int y0  = blockIdx.y * 4;
    const int b   = blockIdx.z;
    __shared__ float sin2[2][1536];     // [buf][ci][row][64]
    __shared__ float swt2[2][1152];     // [buf][ci][tap][32co]
    const int tid = threadIdx.x;
    const int sx = tid & 15;
    const int sy = (tid >> 4) & 3;
    const int cq = tid >> 6;            // wave id == wave-uniform co-group (8 co)

    int in_goff[2];
    bool in_ok[2];
#pragma unroll
    for (int j = 0; j < 2; ++j) {
        int i = tid + j * 256;
        int ci  = i / 96;
        int rem = i - ci * 96;
        int row = rem >> 4;
        int qx  = rem & 15;
        int gy  = y0 + row - 1;
        bool ok = (i < K8_INQ) && gy >= 0 && gy < 64;
        in_ok[j]  = ok;
        in_goff[j] = ok ? (ci * 4096 + gy * 64 + qx * 4) : 0;
    }
    // weight slots: i = tid + j*256, j=0..4 (j=4 only tid<128). i -> [ci][k][cl], cl in 0..31
    int w_goff[5];
#pragma unroll
    for (int j = 0; j < 5; ++j) {
        int i = tid + j * 256;
        int ci  = i / 288;
        int rem = i - ci * 288;
        int k   = rem >> 5;
        int cl  = rem & 31;
        w_goff[j] = (i < K8_WNEL) ? (cl * 864 + ci * 9 + k) : 0;
    }

    const float* xb = xm + (size_t)b * 96 * 4096 + (size_t)ks * 24 * 4096;
    const float* wb = w2 + (size_t)co0 * 864 + ks * 24 * 9;
    const float4 zero4 = make_float4(0.f, 0.f, 0.f, 0.f);

#pragma unroll
    for (int bu = 0; bu < 2; ++bu) {
        if (!in_ok[0]) *(float4*)&sin2[bu][tid * 4] = zero4;
        if (tid < 128 && !in_ok[1]) *(float4*)&sin2[bu][(256 + tid) * 4] = zero4;
    }

    {
        const float* gx = xb;
        const float* gw = wb;
        if (in_ok[0]) async_g2l16_(gx + in_goff[0], &sin2[0][cq * 256]);
        if (tid < 128 && in_ok[1]) async_g2l16_(gx + in_goff[1], &sin2[0][1024 + cq * 256]);
#pragma unroll
        for (int j = 0; j < 4; ++j)
            async_g2l4_(gw + w_goff[j], &swt2[0][j * 256 + cq * 64]);
        if (tid < 128) async_g2l4_(gw + w_goff[4], &swt2[0][1024 + cq * 64]);
    }
    __syncthreads();

    float acc[8][4];
#pragma unroll
    for (int c = 0; c < 8; ++c)
#pragma unroll
        for (int x = 0; x < 4; ++x) acc[c][x] = 0.f;

#pragma clang loop unroll(disable)
    for (int ch = 0; ch < 6; ++ch) {
        if (ch < 5) {
            const int nb = (ch + 1) & 1;
            const float* gx = xb + (ch + 1) * 16384;
            const float* gw = wb + (ch + 1) * 36;
            if (in_ok[0]) async_g2l16_(gx + in_goff[0], &sin2[nb][cq * 256]);
            if (tid < 128 && in_ok[1]) async_g2l16_(gx + in_goff[1], &sin2[nb][1024 + cq * 256]);
#pragma unroll
            for (int j = 0; j < 4; ++j)
                async_g2l4_(gw + w_goff[j], &swt2[nb][j * 256 + cq * 64]);
            if (tid < 128) async_g2l4_(gw + w_goff[4], &swt2[nb][1024 + cq * 64]);
        }

        const float* sc = sin2[ch & 1];
        const float* wc = swt2[ch & 1];
#pragma unroll
        for (int cii = 0; cii < 4; ++cii) {
            float w6[3][6];
#pragma unroll
            for (int r = 0; r < 3; ++r) {
                float4 v = *(const float4*)&sc[(cii * 6 + sy + r) * 64 + sx * 4];
                w6[r][0] = dpp_shift_<0x111>(v.w);   // row_shr:1 -> col 4sx-1
                w6[r][1] = v.x; w6[r][2] = v.y; w6[r][3] = v.z; w6[r][4] = v.w;
                w6[r][5] = dpp_shift_<0x101>(v.x);   // row_shl:1 -> col 4sx+4
            }
#pragma unroll
            for (int ky = 0; ky < 3; ++ky) {
#pragma unroll
                for (int kx = 0; kx < 3; ++kx) {
                    const float* wp = &wc[(cii * 9 + ky * 3 + kx) * 32 + cq * 8];
                    float4 wa = *(const float4*)wp;       // co 0..3 of this group
                    float4 wb4 = *(const float4*)(wp + 4); // co 4..7
#pragma unroll
                    for (int x = 0; x < 4; ++x) {
                        float pv = w6[ky][x + kx];
                        acc[0][x] = fmaf(pv, wa.x, acc[0][x]);
                        acc[1][x] = fmaf(pv, wa.y, acc[1][x]);
                        acc[2][x] = fmaf(pv, wa.z, acc[2][x]);
                        acc[3][x] = fmaf(pv, wa.w, acc[3][x]);
                        acc[4][x] = fmaf(pv, wb4.x, acc[4][x]);
                        acc[5][x] = fmaf(pv, wb4.y, acc[5][x]);
                        acc[6][x] = fmaf(pv, wb4.z, acc[6][x]);
                        acc[7][x] = fmaf(pv, wb4.w, acc[7][x]);
                    }
                }
            }
        }
        __syncthreads();
    }

    const int yy = y0 + sy;
    float* pb = pbuf + (size_t)ks * 1572864;
#pragma unroll
    for (int c = 0; c < 8; ++c) {
        const int cc = co0 + cq * 8 + c;
        float4 o = make_float4(acc[c][0], acc[c][1], acc[c][2], acc[c][3]);
        *(float4*)&pb[((size_t)(b * 96 + cc) * 64 + yy) * 64 + sx * 4] = o;
    }
}

// ---------------- K9: reduce 4 partials + BN + ReLU6 ----------------
__global__ __launch_bounds__(256) void k9_reduce(const float* __restrict__ pbuf,
    const float* __restrict__ bng, const float* __restrict__ bnb,
    const float* __restrict__ bnm, const float* __restrict__ bnv,
    float* __restrict__ out)
{
    const int q = blockIdx.x * 256 + threadIdx.x;   // quad index, 393216 total
    const int idx = q * 4;
    const int c = (idx >> 12) % 96;
    float4 s = *(const float4*)&pbuf[idx];
    float4 s1 = *(const float4*)&pbuf[idx + 1572864];
    float4 s2 = *(const float4*)&pbuf[idx + 2 * 1572864];
    float4 s3 = *(const float4*)&pbuf[idx + 3 * 1572864];
    s.x += s1.x + s2.x + s3.x;
    s.y += s1.y + s2.y + s3.y;
    s.z += s1.z + s2.z + s3.z;
    s.w += s1.w + s2.w + s3.w;
    float inv = bng[c] / sqrtf(bnv[c] + 1e-5f);
    float add = bnb[c] - bnm[c] * inv;
    float4 o;
    o.x = fminf(fmaxf(s.x * inv + add, 0.f), 6.f);
    o.y = fminf(fmaxf(s.y * inv + add, 0.f), 6.f);
    o.z = fminf(fmaxf(s.z * inv + add, 0.f), 6.f);
    o.w = fminf(fmaxf(s.w * inv + add, 0.f), 6.f);
    *(float4*)&out[idx] = o;
}

extern "C" void kernel_launch(void* const* d_in, const int* in_sizes, int n_in,
                              void* d_out, int out_size, void* d_ws, size_t ws_size,
                              hipStream_t stream) {
    (void)in_sizes; (void)n_in; (void)out_size; (void)ws_size;
    const float* x    = (const float*)d_in[0];
    const float* w_in = (const float*)d_in[1];
    const float* cw   = (const float*)d_in[2];
    const float* cb   = (const float*)d_in[3];
    const float* xw   = (const float*)d_in[4];
    const float* dtw  = (const float*)d_in[5];
    const float* dtb  = (const float*)d_in[6];
    const float* alog = (const float*)d_in[7];
    const float* Dp   = (const float*)d_in[8];
    const float* wo   = (const float*)d_in[9];
    const float* w2   = (const float*)d_in[10];
    const float* bng  = (const float*)d_in[11];
    const float* bnb  = (const float*)d_in[12];
    const float* bnm  = (const float*)d_in[13];
    const float* bnv  = (const float*)d_in[14];

    // Lifetime-checked aliasing plan (NCH=256 -> cA/cB are 3,145,728 floats each):
    //   xi_raw [0 .. 3.1M):   k1->k2 input; DEAD k2->k4; cB (k4->k5); yg (k6->k7)
    //   z      [3.1M..6.3M):  k1->k6; then pbuf head (k8->k9)
    //   xi     [6.3M..9.4M):  k2->k6; then pbuf tail (k8->k9)
    //   xdbl   [9.4M..10.06M): k3->k6
    //   cA     [10.06M..13.2M): k4->k6 (hinit aliases, load-before-store in k5);
    //                           then xm (k7->k8)
    float* ws = (float*)d_ws;
    float* xi_raw = ws;
    float* z      = ws + 3145728;
    float* xi     = ws + 6291456;
    float* xdbl   = ws + 9437184;
    float* cA     = ws + 10059776;         // 3,145,728 floats (ends 13,205,504)
    float* cB     = xi_raw;                // alias: xi_raw dead after k2
    float* hinit  = cA;                    // alias: k5 load-before-store
    float* yg     = xi_raw;                // k6 output (cB dead after k5)
    float* xm     = cA;                    // k7 output (cA/hinit dead after k6)
    float* pbuf   = z;                     // 6.3M over z+xi (both dead after k6)

    dim3 blk(256);
    k1_inproj<<<dim3(64, 6, 4), blk, 0, stream>>>(x, w_in, xi_raw, z);
    k2_conv1d<<<dim3(12288), blk, 0, stream>>>(xi_raw, cw, cb, xi);
    k3_xdbl<<<dim3(64, 4), blk, 0, stream>>>(xi, xw, xdbl);
    k4_scanA<<<dim3(NCH, 4), dim3(192), 0, stream>>>(xdbl, xi, dtw, dtb, alog, cA, cB);
    k5_combine<<<dim3(48), blk, 0, stream>>>(cA, cB, hinit);
    k6_scanC<<<dim3(NCH, 4), dim3(192), 0, stream>>>(xdbl, xi, z, dtw, dtb, alog, Dp, hinit, yg);
    k7_outproj<<<dim3(64, 3, 4), blk, 0, stream>>>(yg, wo, xm);
    k8_conv3<<<dim3(12, 16, 4), blk, 0, stream>>>(xm, w2, pbuf);
    k9_reduce<<<dim3(1536), blk, 0, stream>>>(pbuf, bng, bnb, bnm, bnv, (float*)d_out);
}

// Round 17
// 283.419 us; speedup vs baseline: 1.0640x; 1.0640x over previous
//
#include <hip/hip_runtime.h>
#include <math.h>

#define LQ 4096
#define DI 192
#define DS 16
#define NCH 128
#define TCH 32

__device__ __forceinline__ float siluf_(float v) { return v / (1.f + __expf(-v)); }
__device__ __forceinline__ float softplusf_(float v) { return v > 20.f ? v : log1pf(__expf(v)); }

// DPP lane shift within 16-lane rows; bound_ctrl -> 0 at row edges (= image zero-pad).
template <int CTRL>
__device__ __forceinline__ float dpp_shift_(float x) {
    int y = __builtin_amdgcn_update_dpp(0, __float_as_int(x), CTRL, 0xf, 0xf, true);
    return __int_as_float(y);
}
// Async global->LDS. LDS dest = wave-uniform base + lane*size.
__device__ __forceinline__ void async_g2l16_(const float* g, float* l) {
    __builtin_amdgcn_global_load_lds(
        (const __attribute__((address_space(1))) void*)g,
        (__attribute__((address_space(3))) void*)l, 16, 0, 0);
}
__device__ __forceinline__ void async_g2l4_(const float* g, float* l) {
    __builtin_amdgcn_global_load_lds(
        (const __attribute__((address_space(1))) void*)g,
        (__attribute__((address_space(3))) void*)l, 4, 0, 0);
}

// ---------------- K1: in_proj GEMM  xz[b,l,n] = sum_c x[b,c,l] * W[n,c] ----------------
__global__ __launch_bounds__(256) void k1_inproj(const float* __restrict__ x,
    const float* __restrict__ w, float* __restrict__ xi_raw, float* __restrict__ z)
{
    const int l0 = blockIdx.x * 64;
    const int n0 = blockIdx.y * 64;
    const int b  = blockIdx.z;
    __shared__ float xs[96 * 64];    // [c][l]
    __shared__ float wsT[96 * 68];   // [c][n], padded stride 68
    const int tid = threadIdx.x;
    for (int i = tid; i < 96 * 16; i += 256) {
        int c = i >> 4, lq = i & 15;
        *(float4*)&xs[c * 64 + lq * 4] =
            *(const float4*)&x[(b * 96 + c) * LQ + l0 + lq * 4];
    }
    for (int i = tid; i < 64 * 24; i += 256) {
        int n = i / 24, cq = i - n * 24;
        float4 v = *(const float4*)&w[(n0 + n) * 96 + cq * 4];
        wsT[(cq * 4 + 0) * 68 + n] = v.x;
        wsT[(cq * 4 + 1) * 68 + n] = v.y;
        wsT[(cq * 4 + 2) * 68 + n] = v.z;
        wsT[(cq * 4 + 3) * 68 + n] = v.w;
    }
    __syncthreads();
    const int tx = tid & 15;   // n quad
    const int ty = tid >> 4;   // l quad
    float acc[4][4];
#pragma unroll
    for (int i = 0; i < 4; ++i)
#pragma unroll
        for (int j = 0; j < 4; ++j) acc[i][j] = 0.f;
    for (int k = 0; k < 96; ++k) {
        float4 a  = *(const float4*)&xs[k * 64 + ty * 4];
        float4 bb = *(const float4*)&wsT[k * 68 + tx * 4];
        float av[4] = {a.x, a.y, a.z, a.w};
        float bv[4] = {bb.x, bb.y, bb.z, bb.w};
#pragma unroll
        for (int i = 0; i < 4; ++i)
#pragma unroll
            for (int j = 0; j < 4; ++j) acc[i][j] += av[i] * bv[j];
    }
    float* dst = (n0 < DI) ? xi_raw : z;
    const int nn0 = (n0 < DI) ? n0 : (n0 - DI);
#pragma unroll
    for (int i = 0; i < 4; ++i) {
        int l = l0 + ty * 4 + i;
        float4 v = make_float4(acc[i][0], acc[i][1], acc[i][2], acc[i][3]);
        *(float4*)&dst[(b * LQ + l) * DI + nn0 + tx * 4] = v;
    }
}

// ---------------- K2: causal depthwise conv1d + bias + SiLU ----------------
__global__ __launch_bounds__(256) void k2_conv1d(const float* __restrict__ xir,
    const float* __restrict__ cw, const float* __restrict__ cb, float* __restrict__ xi)
{
    int idx = blockIdx.x * 256 + threadIdx.x;       // b*L*DI total
    int d = idx % DI;
    int l = (idx / DI) & (LQ - 1);
    float4 wv = *(const float4*)&cw[d * 4];
    float wk[4] = {wv.x, wv.y, wv.z, wv.w};
    float acc = cb[d];
#pragma unroll
    for (int k = 0; k < 4; ++k) {
        int lp = l - 3 + k;
        if (lp >= 0) acc += wk[k] * xir[idx + (k - 3) * DI];
    }
    xi[idx] = siluf_(acc);
}

// ---------------- K3: x_dbl[b,l,n] = sum_k xi[b,l,k] * xw[n,k], n<38 ----------------
__global__ __launch_bounds__(256) void k3_xdbl(const float* __restrict__ xi,
    const float* __restrict__ xw, float* __restrict__ xdbl)
{
    const int l0 = blockIdx.x * 64;
    const int b  = blockIdx.y;
    __shared__ float sxiT[96 * 68];   // [k(half)][l]
    __shared__ float swx[38 * 196];   // [n][k], padded
    const int tid = threadIdx.x;
    for (int i = tid; i < 38 * 48; i += 256) {
        int n = i / 48, kq = i - n * 48;
        *(float4*)&swx[n * 196 + kq * 4] = *(const float4*)&xw[n * 192 + kq * 4];
    }
    const int lq = tid & 15, ng = tid >> 4;
    float acc[3][4];
#pragma unroll
    for (int p = 0; p < 3; ++p)
#pragma unroll
        for (int i = 0; i < 4; ++i) acc[p][i] = 0.f;
    for (int half = 0; half < 2; ++half) {
        __syncthreads();
        for (int i = tid; i < 64 * 24; i += 256) {
            int l = i / 24, kq = i - l * 24;
            float4 v = *(const float4*)&xi[(b * LQ + l0 + l) * DI + half * 96 + kq * 4];
            sxiT[(kq * 4 + 0) * 68 + l] = v.x;
            sxiT[(kq * 4 + 1) * 68 + l] = v.y;
            sxiT[(kq * 4 + 2) * 68 + l] = v.z;
            sxiT[(kq * 4 + 3) * 68 + l] = v.w;
        }
        __syncthreads();
#pragma unroll
        for (int pass = 0; pass < 3; ++pass) {
            int n = pass * 16 + ng;
            if (n >= 38) continue;
            for (int k = 0; k < 96; ++k) {
                float4 a = *(const float4*)&sxiT[k * 68 + lq * 4];
                float bv = swx[n * 196 + half * 96 + k];
                acc[pass][0] += a.x * bv;
                acc[pass][1] += a.y * bv;
                acc[pass][2] += a.z * bv;
                acc[pass][3] += a.w * bv;
            }
        }
    }
#pragma unroll
    for (int pass = 0; pass < 3; ++pass) {
        int n = pass * 16 + ng;
        if (n >= 38) continue;
#pragma unroll
        for (int i = 0; i < 4; ++i)
            xdbl[(b * LQ + l0 + lq * 4 + i) * 38 + n] = acc[pass][i];
    }
}

// ---------------- K4 v5: scan pass A — 16d x 16s (high TLP), TCH=32 ----------------
// grid (NCH=128, 12, B) = 6144 blocks, block 256, VGPR ~20 -> 32 waves/CU reachable.
__global__ __launch_bounds__(256) void k4_scanA(
    const float* __restrict__ xdbl, const float* __restrict__ xi,
    const float* __restrict__ dtw, const float* __restrict__ dtb,
    const float* __restrict__ alog,
    float* __restrict__ cA, float* __restrict__ cB)
{
    const int ch = blockIdx.x, g = blockIdx.y, b = blockIdx.z;
    const int t0 = ch * TCH, d0 = g * 16;
    __shared__ float sxd[TCH * 40];
    __shared__ float sdt[TCH * 16], sxi[TCH * 16];
    __shared__ float sdtw[96], sdtb[16];
    const int tid = threadIdx.x;
    for (int i = tid; i < TCH * 38; i += 256) {
        int t = i / 38, cc = i - t * 38;
        sxd[t * 40 + cc] = xdbl[(b * LQ + t0 + t) * 38 + cc];
    }
    for (int i = tid; i < TCH * 16; i += 256) {
        int t = i >> 4, j = i & 15;
        sxi[i] = xi[(b * LQ + t0 + t) * DI + d0 + j];
    }
    if (tid < 96) sdtw[tid] = dtw[d0 * 6 + tid];
    if (tid < 16) sdtb[tid] = dtb[d0 + tid];
    __syncthreads();
    for (int i = tid; i < TCH * 16; i += 256) {
        int t = i >> 4, dl = i & 15;
        float acc = sdtb[dl];
#pragma unroll
        for (int r = 0; r < 6; ++r) acc += sxd[t * 40 + r] * sdtw[dl * 6 + r];
        sdt[i] = softplusf_(acc);
    }
    __syncthreads();
    const int s = tid & 15, dl = tid >> 4;
    const float Ads = -__expf(alog[(d0 + dl) * DS + s]);
    float a = 1.f, hb = 0.f;
#pragma unroll 4
    for (int t = 0; t < TCH; ++t) {
        float dtv = sdt[t * 16 + dl];
        float dA = __expf(dtv * Ads);
        float dbx = dtv * sxd[t * 40 + 6 + s] * sxi[t * 16 + dl];
        a *= dA;
        hb = dA * hb + dbx;
    }
    int o = ((b * NCH + ch) * DI + d0 + dl) * DS + s;
    cA[o] = a;
    cB[o] = hb;
}

// ---------------- K5: sequential combine over chunks -> h_init per chunk ----------------
// hinit ALIASES cA (load-before-store per element makes that safe) -> no __restrict__.
__global__ __launch_bounds__(256) void k5_combine(const float* cA,
    const float* __restrict__ cB, float* hinit)
{
    int gid = blockIdx.x * 256 + threadIdx.x;   // 4*192*16 = 12288
    int b = gid / 3072;
    int rem = gid - b * 3072;
    int base = b * (NCH * 3072) + rem;
    float h = 0.f;
#pragma unroll 8
    for (int c = 0; c < NCH; ++c) {
        int o = base + c * 3072;
        float av = cA[o];
        float bv = cB[o];
        hinit[o] = h;
        h = fmaf(av, h, bv);
    }
}

// ---------------- K6 v5: scan pass C — thread = d, h[16] in regs, TCH=32, b128 B/C ----------------
// grid (NCH=128, B) = 512 blocks, block 192. sxd stride 48 (dt@0..5, B@8..23, C@24..39).
__global__ __launch_bounds__(192) void k6_scanC(
    const float* __restrict__ xdbl, const float* __restrict__ xi,
    const float* __restrict__ z, const float* __restrict__ dtw,
    const float* __restrict__ dtb, const float* __restrict__ alog,
    const float* __restrict__ Dp, const float* __restrict__ hinit,
    float* __restrict__ yg)
{
    const int ch = blockIdx.x, b = blockIdx.y;
    const int t0 = ch * TCH;
    __shared__ float sxd[TCH * 48];
    const int d = threadIdx.x;
    for (int i = d; i < TCH * 38; i += 192) {
        int t = i / 38, cc = i - t * 38;
        int slot = cc + (cc >= 6 ? 2 : 0);
        sxd[t * 48 + slot] = xdbl[(b * LQ + t0 + t) * 38 + cc];
    }
    float dtw6[6];
#pragma unroll
    for (int r = 0; r < 6; ++r) dtw6[r] = dtw[d * 6 + r];
    const float dtbd = dtb[d];
    const float Dd = Dp[d];
    float Ads[16];
#pragma unroll
    for (int s = 0; s < 16; ++s) Ads[s] = -__expf(alog[d * 16 + s]);
    float h[16];
    const int o = ((b * NCH + ch) * DI + d) * 16;
#pragma unroll
    for (int s = 0; s < 16; s += 4) {
        float4 v = *(const float4*)&hinit[o + s];
        h[s] = v.x; h[s + 1] = v.y; h[s + 2] = v.z; h[s + 3] = v.w;
    }
    __syncthreads();
    float xiv_next = xi[(b * LQ + t0) * DI + d];
    float zv_next  = z[(b * LQ + t0) * DI + d];
    for (int t = 0; t < TCH; ++t) {
        float xiv = xiv_next, zv = zv_next;
        if (t + 1 < TCH) {
            xiv_next = xi[(b * LQ + t0 + t + 1) * DI + d];
            zv_next  = z[(b * LQ + t0 + t + 1) * DI + d];
        }
        float acc = dtbd;
#pragma unroll
        for (int r = 0; r < 6; ++r) acc = fmaf(sxd[t * 48 + r], dtw6[r], acc);
        float dtv = softplusf_(acc);
        float dtxi = dtv * xiv;
        const float* Bp = &sxd[t * 48 + 8];
        const float* Cp = &sxd[t * 48 + 24];
        float Bv[16], Cv[16];
#pragma unroll
        for (int q = 0; q < 4; ++q) {
            float4 vb = *(const float4*)(Bp + q * 4);
            float4 vc = *(const float4*)(Cp + q * 4);
            Bv[q * 4] = vb.x; Bv[q * 4 + 1] = vb.y; Bv[q * 4 + 2] = vb.z; Bv[q * 4 + 3] = vb.w;
            Cv[q * 4] = vc.x; Cv[q * 4 + 1] = vc.y; Cv[q * 4 + 2] = vc.z; Cv[q * 4 + 3] = vc.w;
        }
        float y0 = 0.f, y1 = 0.f, y2 = 0.f, y3 = 0.f;
#pragma unroll
        for (int s = 0; s < 16; s += 4) {
            float dA0 = __expf(dtv * Ads[s]);
            float dA1 = __expf(dtv * Ads[s + 1]);
            float dA2 = __expf(dtv * Ads[s + 2]);
            float dA3 = __expf(dtv * Ads[s + 3]);
            h[s]     = fmaf(dA0, h[s],     dtxi * Bv[s]);
            h[s + 1] = fmaf(dA1, h[s + 1], dtxi * Bv[s + 1]);
            h[s + 2] = fmaf(dA2, h[s + 2], dtxi * Bv[s + 2]);
            h[s + 3] = fmaf(dA3, h[s + 3], dtxi * Bv[s + 3]);
            y0 = fmaf(h[s],     Cv[s],     y0);
            y1 = fmaf(h[s + 1], Cv[s + 1], y1);
            y2 = fmaf(h[s + 2], Cv[s + 2], y2);
            y3 = fmaf(h[s + 3], Cv[s + 3], y3);
        }
        float y = (y0 + y1) + (y2 + y3);
        float gate = siluf_(zv);
        yg[(b * LQ + t0 + t) * DI + d] = (y + xiv * Dd) * gate;
    }
}

// ---------------- K7: out_proj GEMM, store transposed to NCHW xm[b,c,l] ----------------
__global__ __launch_bounds__(256) void k7_outproj(const float* __restrict__ yg,
    const float* __restrict__ wo, float* __restrict__ xm)
{
    const int l0 = blockIdx.x * 64;
    const int n0 = blockIdx.y * 32;
    const int b  = blockIdx.z;
    __shared__ float syT[96 * 68];    // [k(half)][l]
    __shared__ float wtT[192 * 36];   // [k][n]
    const int tid = threadIdx.x;
    for (int i = tid; i < 32 * 48; i += 256) {
        int n = i / 48, kq = i - n * 48;
        float4 v = *(const float4*)&wo[(n0 + n) * DI + kq * 4];
        wtT[(kq * 4 + 0) * 36 + n] = v.x;
        wtT[(kq * 4 + 1) * 36 + n] = v.y;
        wtT[(kq * 4 + 2) * 36 + n] = v.z;
        wtT[(kq * 4 + 3) * 36 + n] = v.w;
    }
    const int tx = tid & 15;   // l quad
    const int ty = tid >> 4;   // n pair
    float acc[2][4];
#pragma unroll
    for (int j = 0; j < 2; ++j)
#pragma unroll
        for (int i = 0; i < 4; ++i) acc[j][i] = 0.f;
    for (int half = 0; half < 2; ++half) {
        __syncthreads();
        for (int i = tid; i < 64 * 24; i += 256) {
            int l = i / 24, kq = i - l * 24;
            float4 v = *(const float4*)&yg[(b * LQ + l0 + l) * DI + half * 96 + kq * 4];
            syT[(kq * 4 + 0) * 68 + l] = v.x;
            syT[(kq * 4 + 1) * 68 + l] = v.y;
            syT[(kq * 4 + 2) * 68 + l] = v.z;
            syT[(kq * 4 + 3) * 68 + l] = v.w;
        }
        __syncthreads();
        for (int k = 0; k < 96; ++k) {
            float4 a = *(const float4*)&syT[k * 68 + tx * 4];
            int kk = half * 96 + k;
            float b0 = wtT[kk * 36 + ty * 2 + 0];
            float b1 = wtT[kk * 36 + ty * 2 + 1];
            acc[0][0] += a.x * b0; acc[0][1] += a.y * b0;
            acc[0][2] += a.z * b0; acc[0][3] += a.w * b0;
            acc[1][0] += a.x * b1; acc[1][1] += a.y * b1;
            acc[1][2] += a.z * b1; acc[1][3] += a.w * b1;
        }
    }
#pragma unroll
    for (int j = 0; j < 2; ++j) {
        float4 v = make_float4(acc[j][0], acc[j][1], acc[j][2], acc[j][3]);
        *(float4*)&xm[(b * 96 + n0 + ty * 2 + j) * LQ + l0 + tx * 4] = v;
    }
}

// ---------------- K8 v12: 3x3 conv partials — async global_load_lds + LDS dbuf ----------------
#define K8_INQ 384              // staged float4 quads per chunk
#define K8_WNEL 576             // staged weight floats per chunk
__global__ __launch_bounds__(256) void k8_conv3(const float* __restrict__ xm,
    const float* __restrict__ w2, float* __restrict__ pbuf)
{
    const int ks  = blockIdx.x & 3;
    const int co0 = (blockIdx.x >> 2) * 16;
    const int y0  = blockIdx.y * 4;
    const int b   = blockIdx.z;
    __shared__ float sin2[2][1536];     // [buf][ci][row][64]
    __shared__ float swt2[2][576];      // [buf][ci][tap][16co]
    const int tid = threadIdx.x;
    const int sx = tid & 15;
    const int sy = (tid >> 4) & 3;
    const int cq = tid >> 6;            // wave id == wave-uniform co-quad

    int in_goff[2];
    bool in_ok[2];
#pragma unroll
    for (int j = 0; j < 2; ++j) {
        int i = tid + j * 256;
        int ci  = i / 96;
        int rem = i - ci * 96;
        int row = rem >> 4;
        int qx  = rem & 15;
        int gy  = y0 + row - 1;
        bool ok = (i < K8_INQ) && gy >= 0 && gy < 64;
        in_ok[j]  = ok;
        in_goff[j] = ok ? (ci * 4096 + gy * 64 + qx * 4) : 0;
    }
    int w_goff[3];
#pragma unroll
    for (int j = 0; j < 3; ++j) {
        int i = tid + j * 256;
        int ci  = i / 144;
        int rem = i - ci * 144;
        int k   = rem >> 4;
        int cl  = rem & 15;
        w_goff[j] = (i < K8_WNEL) ? (cl * 864 + ci * 9 + k) : 0;
    }

    const float* xb = xm + (size_t)b * 96 * 4096 + (size_t)ks * 24 * 4096;
    const float* wb = w2 + (size_t)co0 * 864 + ks * 24 * 9;
    const float4 zero4 = make_float4(0.f, 0.f, 0.f, 0.f);

#pragma unroll
    for (int bu = 0; bu < 2; ++bu) {
        if (!in_ok[0]) *(float4*)&sin2[bu][tid * 4] = zero4;
        if (tid < 128 && !in_ok[1]) *(float4*)&sin2[bu][(256 + tid) * 4] = zero4;
    }

    {
        const float* gx = xb;
        const float* gw = wb;
        if (in_ok[0]) async_g2l16_(gx + in_goff[0], &sin2[0][cq * 256]);
        if (tid < 128 && in_ok[1]) async_g2l16_(gx + in_goff[1], &sin2[0][1024 + cq * 256]);
        async_g2l4_(gw + w_goff[0], &swt2[0][cq * 64]);
        async_g2l4_(gw + w_goff[1], &swt2[0][256 + cq * 64]);
        if (tid < 64) async_g2l4_(gw + w_goff[2], &swt2[0][512 + cq * 64]);
    }
    __syncthreads();

    float acc[4][4];
#pragma unroll
    for (int c = 0; c < 4; ++c)
#pragma unroll
        for (int x = 0; x < 4; ++x) acc[c][x] = 0.f;

#pragma clang loop unroll(disable)
    for (int ch = 0; ch < 6; ++ch) {
        if (ch < 5) {
            const int nb = (ch + 1) & 1;
            const float* gx = xb + (ch + 1) * 16384;
            const float* gw = wb + (ch + 1) * 36;
            if (in_ok[0]) async_g2l16_(gx + in_goff[0], &sin2[nb][cq * 256]);
            if (tid < 128 && in_ok[1]) async_g2l16_(gx + in_goff[1], &sin2[nb][1024 + cq * 256]);
            async_g2l4_(gw + w_goff[0], &swt2[nb][cq * 64]);
            async_g2l4_(gw + w_goff[1], &swt2[nb][256 + cq * 64]);
            if (tid < 64) async_g2l4_(gw + w_goff[2], &swt2[nb][512 + cq * 64]);
        }

        const float* sc = sin2[ch & 1];
        const float* wc = swt2[ch & 1];
#pragma unroll
        for (int cii = 0; cii < 4; ++cii) {
            float w6[3][6];
#pragma unroll
            for (int r = 0; r < 3; ++r) {
                float4 v = *(const float4*)&sc[(cii * 6 + sy + r) * 64 + sx * 4];
                w6[r][0] = dpp_shift_<0x111>(v.w);   // row_shr:1 -> col 4sx-1
                w6[r][1] = v.x; w6[r][2] = v.y; w6[r][3] = v.z; w6[r][4] = v.w;
                w6[r][5] = dpp_shift_<0x101>(v.x);   // row_shl:1 -> col 4sx+4
            }
#pragma unroll
            for (int ky = 0; ky < 3; ++ky) {
#pragma unroll
                for (int kx = 0; kx < 3; ++kx) {
                    float4 wv = *(const float4*)&wc[(cii * 9 + ky * 3 + kx) * 16 + cq * 4];
#pragma unroll
                    for (int x = 0; x < 4; ++x) {
                        float pv = w6[ky][x + kx];
                        acc[0][x] = fmaf(pv, wv.x, acc[0][x]);
                        acc[1][x] = fmaf(pv, wv.y, acc[1][x]);
                        acc[2][x] = fmaf(pv, wv.z, acc[2][x]);
                        acc[3][x] = fmaf(pv, wv.w, acc[3][x]);
                    }
                }
            }
        }
        __syncthreads();
    }

    const int yy = y0 + sy;
    float* pb = pbuf + (size_t)ks * 1572864;
#pragma unroll
    for (int c = 0; c < 4; ++c) {
        const int cc = co0 + cq * 4 + c;
        float4 o = make_float4(acc[c][0], acc[c][1], acc[c][2], acc[c][3]);
        *(float4*)&pb[((size_t)(b * 96 + cc) * 64 + yy) * 64 + sx * 4] = o;
    }
}

// ---------------- K9: reduce 4 partials + BN + ReLU6 ----------------
__global__ __launch_bounds__(256) void k9_reduce(const float* __restrict__ pbuf,
    const float* __restrict__ bng, const float* __restrict__ bnb,
    const float* __restrict__ bnm, const float* __restrict__ bnv,
    float* __restrict__ out)
{
    const int q = blockIdx.x * 256 + threadIdx.x;   // quad index, 393216 total
    const int idx = q * 4;
    const int c = (idx >> 12) % 96;
    float4 s = *(const float4*)&pbuf[idx];
    float4 s1 = *(const float4*)&pbuf[idx + 1572864];
    float4 s2 = *(const float4*)&pbuf[idx + 2 * 1572864];
    float4 s3 = *(const float4*)&pbuf[idx + 3 * 1572864];
    s.x += s1.x + s2.x + s3.x;
    s.y += s1.y + s2.y + s3.y;
    s.z += s1.z + s2.z + s3.z;
    s.w += s1.w + s2.w + s3.w;
    float inv = bng[c] / sqrtf(bnv[c] + 1e-5f);
    float add = bnb[c] - bnm[c] * inv;
    float4 o;
    o.x = fminf(fmaxf(s.x * inv + add, 0.f), 6.f);
    o.y = fminf(fmaxf(s.y * inv + add, 0.f), 6.f);
    o.z = fminf(fmaxf(s.z * inv + add, 0.f), 6.f);
    o.w = fminf(fmaxf(s.w * inv + add, 0.f), 6.f);
    *(float4*)&out[idx] = o;
}

extern "C" void kernel_launch(void* const* d_in, const int* in_sizes, int n_in,
                              void* d_out, int out_size, void* d_ws, size_t ws_size,
                              hipStream_t stream) {
    (void)in_sizes; (void)n_in; (void)out_size; (void)ws_size;
    const float* x    = (const float*)d_in[0];
    const float* w_in = (const float*)d_in[1];
    const float* cw   = (const float*)d_in[2];
    const float* cb   = (const float*)d_in[3];
    const float* xw   = (const float*)d_in[4];
    const float* dtw  = (const float*)d_in[5];
    const float* dtb  = (const float*)d_in[6];
    const float* alog = (const float*)d_in[7];
    const float* Dp   = (const float*)d_in[8];
    const float* wo   = (const float*)d_in[9];
    const float* w2   = (const float*)d_in[10];
    const float* bng  = (const float*)d_in[11];
    const float* bnb  = (const float*)d_in[12];
    const float* bnm  = (const float*)d_in[13];
    const float* bnv  = (const float*)d_in[14];

    // r13-proven layout (NCH=128 -> cA/cB = 1,572,864 floats each):
    float* ws = (float*)d_ws;
    float* xi_raw = ws;                    // k1->k2; yg (k6->k7); pbuf head (k8->k9)
    float* z      = ws + 3145728;          // k1->k6; pbuf tail
    float* xi     = ws + 6291456;          // k2->k6
    float* xdbl   = ws + 9437184;          // k3->k6
    float* cA     = ws + 10059776;         // k4->k5; hinit (k5->k6); then dead
    float* cB     = ws + 11632640;         // k4->k5; xm (k7->k8)
    float* hinit  = cA;                    // alias: k5 load-before-store
    float* xm     = cB;                    // alias: cB dead after k5
    float* yg     = xi_raw;
    float* pbuf   = xi_raw;                // 4 x 1,572,864 over xi_raw+z

    dim3 blk(256);
    k1_inproj<<<dim3(64, 6, 4), blk, 0, stream>>>(x, w_in, xi_raw, z);
    k2_conv1d<<<dim3(12288), blk, 0, stream>>>(xi_raw, cw, cb, xi);
    k3_xdbl<<<dim3(64, 4), blk, 0, stream>>>(xi, xw, xdbl);
    k4_scanA<<<dim3(NCH, 12, 4), blk, 0, stream>>>(xdbl, xi, dtw, dtb, alog, cA, cB);
    k5_combine<<<dim3(48), blk, 0, stream>>>(cA, cB, hinit);
    k6_scanC<<<dim3(NCH, 4), dim3(192), 0, stream>>>(xdbl, xi, z, dtw, dtb, alog, Dp, hinit, yg);
    k7_outproj<<<dim3(64, 3, 4), blk, 0, stream>>>(yg, wo, xm);
    k8_conv3<<<dim3(24, 16, 4), blk, 0, stream>>>(xm, w2, pbuf);
    k9_reduce<<<dim3(1536), blk, 0, stream>>>(pbuf, bng, bnb, bnm, bnv, (float*)d_out);
}